// Round 2
// baseline (11766.408 us; speedup 1.0000x reference)
//
#include <hip/hip_runtime.h>

#define BB 128
#define TT 1024
#define FF 256
#define UU 512
#define NG 8      // batch groups
#define BT 16     // batch per group
#define CWG 32    // col-WGs per group
#define UW 16     // units per WG

typedef __bf16 bf16x8 __attribute__((ext_vector_type(8)));
typedef float f32x4 __attribute__((ext_vector_type(4)));
typedef float f32x2 __attribute__((ext_vector_type(2)));

union U16F { uint4 u; bf16x8 b; };

__device__ __forceinline__ unsigned short f2bf(float f) {
    unsigned int u = __float_as_uint(f);
    u += 0x7FFFu + ((u >> 16) & 1u);
    return (unsigned short)(u >> 16);
}

__device__ __forceinline__ float fsig(float x) { return 1.0f / (1.0f + __expf(-x)); }
__device__ __forceinline__ float ftanh(float x) {
    float xc = fminf(fmaxf(x, -15.0f), 15.0f);
    float e = __expf(2.0f * xc);
    return (e - 1.0f) / (e + 1.0f);
}

// ws layout: [0, 262144) h double buffer (bf16 [2][128][512])
//            [262144, 263168) flags (int [NG][CWG])
//            [266240, 528384) pwT (bf16 [512][256])

__global__ void __launch_bounds__(256, 1) lstm_kernel(
    const float* __restrict__ x, const float* __restrict__ wk,
    const float* __restrict__ wr, const float* __restrict__ bias,
    float* __restrict__ out, void* ws)
{
    unsigned short* hbuf = (unsigned short*)ws;
    int* flags = (int*)((char*)ws + 262144);

    const int tid = threadIdx.x;
    const int l = tid & 63;
    const int w = tid >> 6;            // wave id == gate id (0:i 1:f 2:g 3:o)
    const int g = blockIdx.x & 7;      // group (XCD-friendly mapping)
    const int cw = blockIdx.x >> 3;    // col-WG within group

    __shared__ __align__(16) unsigned short xlds[16 * 256]; // 8KB, swizzled
    __shared__ __align__(16) unsigned short hlds[16 * 512]; // 16KB, swizzled
    __shared__ float zbuf[4][16][16];                        // 4KB
    __shared__ int abortf;

    const int ncol = l & 15;
    const int kq = l >> 4;

    // ---- Load weight slice into register B-fragments (bf16) ----
    // B[k][n]: n = lane&15 -> gate col; k = kb*32 + kq*8 + e
    U16F bfr[24];
    const int gcol = w * UU + cw * UW + ncol;
#pragma unroll
    for (int kb = 0; kb < 24; ++kb) {
        const int k0 = kb * 32 + kq * 8;
        const float* src = (kb < 8) ? (wk + (size_t)k0 * 2048 + gcol)
                                    : (wr + (size_t)(k0 - 256) * 2048 + gcol);
        unsigned short h[8];
#pragma unroll
        for (int e = 0; e < 8; ++e) h[e] = f2bf(src[(size_t)e * 2048]);
        bfr[kb].u.x = h[0] | ((unsigned)h[1] << 16);
        bfr[kb].u.y = h[2] | ((unsigned)h[3] << 16);
        bfr[kb].u.z = h[4] | ((unsigned)h[5] << 16);
        bfr[kb].u.w = h[6] | ((unsigned)h[7] << 16);
    }

    // gate-phase mapping: threads 0..127, TWO adjacent units per thread
    const int gm = tid >> 3;           // batch-local row (valid for tid<128)
    const int jp = tid & 7;
    const int unit0 = cw * UW + jp * 2;
    const float bi0 = bias[unit0],          bi1 = bias[unit0 + 1];
    const float bf0 = bias[UU + unit0],     bf1 = bias[UU + unit0 + 1];
    const float bg0 = bias[2 * UU + unit0], bg1 = bias[2 * UU + unit0 + 1];
    const float bo0 = bias[3 * UU + unit0], bo1 = bias[3 * UU + unit0 + 1];
    float c0 = 0.0f, c1 = 0.0f;
    const int gb = g * BT;

    if (tid == 0) abortf = 0;
    __syncthreads();

    for (int t = 0; t < TT; ++t) {
        const int rp = t & 1;
        const int wp = rp ^ 1;

        // ---- stage x_t tile -> LDS (bf16, XOR-swizzled); overlaps the wait ----
#pragma unroll
        for (int i = 0; i < 4; ++i) {
            const int chunk = tid + 256 * i;
            const int m = chunk >> 6, c4 = chunk & 63;
            const float4 v = *(const float4*)(x + ((size_t)(gb + m) * TT + t) * FF + c4 * 4);
            const unsigned lo = f2bf(v.x) | ((unsigned)f2bf(v.y) << 16);
            const unsigned hi = f2bf(v.z) | ((unsigned)f2bf(v.w) << 16);
            const int off = (m * 512 + c4 * 8) ^ ((m & 7) << 4);
            uint2 pv; pv.x = lo; pv.y = hi;
            *(uint2*)((char*)xlds + off) = pv;
        }

        // ---- wait for h_{t-1} from all 32 peers of this group ----
        {
            int* fp = flags + g * CWG + (l & 31);
            int guard = 0;
            while (1) {
                int v = __hip_atomic_load(fp, __ATOMIC_RELAXED, __HIP_MEMORY_SCOPE_AGENT);
                if (__all(v >= t)) break;
                if (++guard > 4000000) { abortf = 1; break; }
                __builtin_amdgcn_s_sleep(1);
            }
            __builtin_amdgcn_fence(__ATOMIC_ACQUIRE, "agent");
        }

        // ---- stage h tile -> LDS via sc1 atomic loads (bypass L1/L2: no staleness) ----
        const unsigned long long* hsrc =
            (const unsigned long long*)(hbuf + (size_t)rp * (BB * UU));
#pragma unroll
        for (int i = 0; i < 8; ++i) {
            const int chunk = tid + 256 * i;      // 0..2047
            const int m = chunk >> 7;             // 0..15
            const int c8 = chunk & 127;           // 0..127 (4 bf16 per 8B)
            const unsigned long long v = __hip_atomic_load(
                hsrc + (size_t)(gb + m) * 128 + c8,
                __ATOMIC_RELAXED, __HIP_MEMORY_SCOPE_AGENT);
            const int off = (m * 1024 + c8 * 8) ^ ((m & 7) << 4);
            *(unsigned long long*)((char*)hlds + off) = v;
        }
        __syncthreads();
        if (abortf) break;

        // ---- MFMA: z-tile [16 batch x 16 cols] for this wave's gate ----
        f32x4 acc = {0.f, 0.f, 0.f, 0.f};
        const int am = ncol; // A row = lane&15 (batch-local)
#pragma unroll
        for (int kb = 0; kb < 8; ++kb) {
            U16F a;
            const int off = (am * 512 + kb * 64 + kq * 16) ^ ((am & 7) << 4);
            a.u = *(const uint4*)((const char*)xlds + off);
            acc = __builtin_amdgcn_mfma_f32_16x16x32_bf16(a.b, bfr[kb].b, acc, 0, 0, 0);
        }
#pragma unroll
        for (int kb = 0; kb < 16; ++kb) {
            U16F a;
            const int off = (am * 1024 + kb * 64 + kq * 16) ^ ((am & 7) << 4);
            a.u = *(const uint4*)((const char*)hlds + off);
            acc = __builtin_amdgcn_mfma_f32_16x16x32_bf16(a.b, bfr[8 + kb].b, acc, 0, 0, 0);
        }
        // D: col = lane&15, row = kq*4 + r
#pragma unroll
        for (int r = 0; r < 4; ++r) zbuf[w][kq * 4 + r][ncol] = acc[r];
        __syncthreads();

        // ---- gates + cell update (two adjacent cells per thread, tid<128) ----
        if (tid < 128) {
            const float zi0 = zbuf[0][gm][jp * 2]     + bi0;
            const float zi1 = zbuf[0][gm][jp * 2 + 1] + bi1;
            const float zf0 = zbuf[1][gm][jp * 2]     + bf0;
            const float zf1 = zbuf[1][gm][jp * 2 + 1] + bf1;
            const float zg0 = zbuf[2][gm][jp * 2]     + bg0;
            const float zg1 = zbuf[2][gm][jp * 2 + 1] + bg1;
            const float zo0 = zbuf[3][gm][jp * 2]     + bo0;
            const float zo1 = zbuf[3][gm][jp * 2 + 1] + bo1;
            c0 = fsig(zf0) * c0 + fsig(zi0) * ftanh(zg0);
            c1 = fsig(zf1) * c1 + fsig(zi1) * ftanh(zg1);
            const float h0 = fsig(zo0) * ftanh(c0);
            const float h1 = fsig(zo1) * ftanh(c1);

            // lstm_out -> d_out (nontemporal pair; keeps L2 clean)
            f32x2 hv; hv[0] = h0; hv[1] = h1;
            __builtin_nontemporal_store(
                hv, (f32x2*)(out + ((size_t)(gb + gm) * TT + t) * UU + unit0));

            // h_t -> global: one sc1 32-bit store (2 bf16), no shfl pairing
            const unsigned word = (unsigned)f2bf(h0) | ((unsigned)f2bf(h1) << 16);
            __hip_atomic_store(
                (unsigned*)(hbuf + (size_t)wp * (BB * UU) + (size_t)(gb + gm) * UU + unit0),
                word, __ATOMIC_RELAXED, __HIP_MEMORY_SCOPE_AGENT);
        }
        __syncthreads();  // drains vmcnt: all sc1 h stores at coherence point
        if (tid == 0)
            __hip_atomic_store(flags + g * CWG + cw, t + 1,
                               __ATOMIC_RELAXED, __HIP_MEMORY_SCOPE_AGENT);
    }
}

// proj_w [256][512] f32 -> pwT [512][256] bf16
__global__ void prep_kernel(const float* __restrict__ pw, unsigned short* __restrict__ pwT) {
    const int e = blockIdx.x * 256 + threadIdx.x;
    const int n = e >> 8, k = e & 255;
    pwT[e] = f2bf(pw[(size_t)k * UU + n]);
}

// residual GEMM + add h + layernorm, in-place on d_out. 16 rows / block.
__global__ void __launch_bounds__(256) ln_kernel(
    const float* __restrict__ x, const unsigned short* __restrict__ pwT,
    const float* __restrict__ pb, const float* __restrict__ gamma,
    const float* __restrict__ beta, float* __restrict__ out)
{
    const int tid = threadIdx.x;
    const int l = tid & 63;
    const int w = tid >> 6;
    const int r0 = blockIdx.x * 16;
    __shared__ float ybuf[16 * 516];

    const int ncol = l & 15, kq = l >> 4;
    U16F af[8];
    const int arow = r0 + ncol;
#pragma unroll
    for (int kb = 0; kb < 8; ++kb) {
        const float* src = x + (size_t)arow * FF + kb * 32 + kq * 8;
        const float4 v0 = *(const float4*)(src);
        const float4 v1 = *(const float4*)(src + 4);
        af[kb].u.x = f2bf(v0.x) | ((unsigned)f2bf(v0.y) << 16);
        af[kb].u.y = f2bf(v0.z) | ((unsigned)f2bf(v0.w) << 16);
        af[kb].u.z = f2bf(v1.x) | ((unsigned)f2bf(v1.y) << 16);
        af[kb].u.w = f2bf(v1.z) | ((unsigned)f2bf(v1.w) << 16);
    }
#pragma unroll
    for (int nt = 0; nt < 8; ++nt) {
        const int colb = w * 128 + nt * 16;
        f32x4 acc = {0.f, 0.f, 0.f, 0.f};
#pragma unroll
        for (int kb = 0; kb < 8; ++kb) {
            U16F bf;
            bf.u = *(const uint4*)(pwT + (size_t)(colb + ncol) * FF + kb * 32 + kq * 8);
            acc = __builtin_amdgcn_mfma_f32_16x16x32_bf16(af[kb].b, bf.b, acc, 0, 0, 0);
        }
        const int col = colb + ncol;
        const float pbv = pb[col];
#pragma unroll
        for (int r = 0; r < 4; ++r) {
            const int row = kq * 4 + r;
            const float hv = out[(size_t)(r0 + row) * UU + col];
            ybuf[row * 516 + col] = acc[r] + pbv + hv;
        }
    }
    __syncthreads();
    const int m = tid >> 4, j = tid & 15;
    float s = 0.f, s2 = 0.f;
#pragma unroll
    for (int i = 0; i < 32; ++i) {
        const float v = ybuf[m * 516 + j + 16 * i];
        s += v; s2 += v * v;
    }
#pragma unroll
    for (int mask = 1; mask < 16; mask <<= 1) {
        s += __shfl_xor(s, mask);
        s2 += __shfl_xor(s2, mask);
    }
    const float mean = s * (1.0f / 512.0f);
    const float var = s2 * (1.0f / 512.0f) - mean * mean;
    const float rs = rsqrtf(var + 1e-6f);
#pragma unroll
    for (int i = 0; i < 32; ++i) {
        const int col = j + 16 * i;
        const float v = ybuf[m * 516 + col];
        out[(size_t)(r0 + m) * UU + col] = gamma[col] * ((v - mean) * rs) + beta[col];
    }
}

extern "C" void kernel_launch(void* const* d_in, const int* in_sizes, int n_in,
                              void* d_out, int out_size, void* d_ws, size_t ws_size,
                              hipStream_t stream) {
    const float* x     = (const float*)d_in[0];
    const float* wk    = (const float*)d_in[1];
    const float* wr    = (const float*)d_in[2];
    const float* bias  = (const float*)d_in[3];
    const float* pw    = (const float*)d_in[4];
    const float* pb    = (const float*)d_in[5];
    const float* gamma = (const float*)d_in[6];
    const float* beta  = (const float*)d_in[7];
    float* out = (float*)d_out;

    if (ws_size < 528384) return;  // need ~516KB scratch

    unsigned short* pwT = (unsigned short*)((char*)d_ws + 266240);

    // zero h double-buffer + flags
    hipMemsetAsync(d_ws, 0, 263168, stream);
    hipLaunchKernelGGL(prep_kernel, dim3(512), dim3(256), 0, stream, pw, pwT);

    // cooperative launch: guarantees all 256 WGs co-resident (spin barriers)
    const float* a0 = x; const float* a1 = wk; const float* a2 = wr;
    const float* a3 = bias; float* a4 = out; void* a5 = d_ws;
    void* args[6] = {(void*)&a0, (void*)&a1, (void*)&a2, (void*)&a3, (void*)&a4, (void*)&a5};
    hipError_t ce = hipLaunchCooperativeKernel((const void*)lstm_kernel, dim3(256), dim3(256),
                                               args, 0, stream);
    if (ce != hipSuccess) {
        // fallback: plain launch (1 WG/CU, 256 WGs on 256 CUs -> co-resident)
        hipLaunchKernelGGL(lstm_kernel, dim3(256), dim3(256), 0, stream,
                           x, wk, wr, bias, out, d_ws);
    }

    hipLaunchKernelGGL(ln_kernel, dim3(BB * TT / 16), dim3(256), 0, stream,
                       x, pwT, pb, gamma, beta, out);
}

// Round 3
// 3455.350 us; speedup vs baseline: 3.4053x; 3.4053x over previous
//
#include <hip/hip_runtime.h>

#define BB 128
#define TT 1024
#define FF 256
#define UU 512
#define NG 8      // batch groups
#define BT 16     // batch per group
#define CWG 32    // col-WGs per group
#define UW 16     // units per WG

typedef __bf16 bf16x8 __attribute__((ext_vector_type(8)));
typedef float f32x4 __attribute__((ext_vector_type(4)));
typedef float f32x2 __attribute__((ext_vector_type(2)));
typedef unsigned int u32x4 __attribute__((ext_vector_type(4)));

union U16F { u32x4 u; bf16x8 b; };

__device__ __forceinline__ unsigned short f2bf(float f) {
    unsigned int u = __float_as_uint(f);
    u += 0x7FFFu + ((u >> 16) & 1u);
    return (unsigned short)(u >> 16);
}

__device__ __forceinline__ float fsig(float x) { return 1.0f / (1.0f + __expf(-x)); }
__device__ __forceinline__ float ftanh(float x) {
    float xc = fminf(fmaxf(x, -15.0f), 15.0f);
    float e = __expf(2.0f * xc);
    return (e - 1.0f) / (e + 1.0f);
}

// ws layout: [0, 262144) h double buffer (bf16 [2][128][512])
//            [262144, 263168) flags (int [NG][CWG])
//            [266240, 528384) pwT (bf16 [512][256])

__global__ void __launch_bounds__(256, 1) lstm_kernel(
    const float* __restrict__ x, const float* __restrict__ wk,
    const float* __restrict__ wr, const float* __restrict__ bias,
    float* __restrict__ out, void* ws)
{
    unsigned short* hbuf = (unsigned short*)ws;
    int* flags = (int*)((char*)ws + 262144);

    const int tid = threadIdx.x;
    const int l = tid & 63;
    const int w = tid >> 6;            // wave id == gate id (0:i 1:f 2:g 3:o)
    const int g = blockIdx.x & 7;      // group
    const int cw = blockIdx.x >> 3;    // col-WG within group

    __shared__ __align__(16) unsigned short xlds[16 * 256]; // 8KB, swizzled
    __shared__ __align__(16) unsigned short hlds[16 * 512]; // 16KB, swizzled
    __shared__ float zbuf[4][16][16];                        // 4KB
    __shared__ int abortf;

    const int ncol = l & 15;
    const int kq = l >> 4;

    // ---- Load weight slice into register B-fragments (bf16) ----
    U16F bfr[24];
    const int gcol = w * UU + cw * UW + ncol;
#pragma unroll
    for (int kb = 0; kb < 24; ++kb) {
        const int k0 = kb * 32 + kq * 8;
        const float* src = (kb < 8) ? (wk + (size_t)k0 * 2048 + gcol)
                                    : (wr + (size_t)(k0 - 256) * 2048 + gcol);
        unsigned short h[8];
#pragma unroll
        for (int e = 0; e < 8; ++e) h[e] = f2bf(src[(size_t)e * 2048]);
        bfr[kb].u.x = h[0] | ((unsigned)h[1] << 16);
        bfr[kb].u.y = h[2] | ((unsigned)h[3] << 16);
        bfr[kb].u.z = h[4] | ((unsigned)h[5] << 16);
        bfr[kb].u.w = h[6] | ((unsigned)h[7] << 16);
    }

    const float bv = bias[gcol];       // folded into MFMA C-init

    // gate-phase mapping: threads 0..127, TWO adjacent units per thread
    const int gm = tid >> 3;
    const int jp = tid & 7;
    const int unit0 = cw * UW + jp * 2;
    float c0 = 0.0f, c1 = 0.0f;
    float ph0 = 0.0f, ph1 = 0.0f;      // previous step's h (deferred out-store)
    const int gb = g * BT;
    const int c16 = tid & 63;          // h-stage column chunk (16B units)

    if (tid == 0) abortf = 0;
    __syncthreads();

    for (int t = 0; t < TT; ++t) {
        const int rp = t & 1;
        const int wp = rp ^ 1;

        // ---- stage x_t tile -> LDS (bf16, XOR-swizzled) ----
#pragma unroll
        for (int i = 0; i < 4; ++i) {
            const int chunk = tid + 256 * i;
            const int m = chunk >> 6, c4 = chunk & 63;
            const float4 v = *(const float4*)(x + ((size_t)(gb + m) * TT + t) * FF + c4 * 4);
            const unsigned lo = f2bf(v.x) | ((unsigned)f2bf(v.y) << 16);
            const unsigned hi = f2bf(v.z) | ((unsigned)f2bf(v.w) << 16);
            const int off = (m * 512 + c4 * 8) ^ ((m & 7) << 4);
            uint2 pv; pv.x = lo; pv.y = hi;
            *(uint2*)((char*)xlds + off) = pv;
        }
        __syncthreads();   // bar A: xlds ready (drains x loads; prev out-store long done)

        // deferred out-store of h_{t-1}: drains during the poll window below
        if (t && tid < 128) {
            f32x2 hv; hv[0] = ph0; hv[1] = ph1;
            __builtin_nontemporal_store(
                hv, (f32x2*)(out + ((size_t)(gb + gm) * TT + (t - 1)) * UU + unit0));
        }

        // ---- x-part MFMA (independent of h; off the post-flag path) ----
        f32x4 acc = {bv, bv, bv, bv};
        const int am = ncol;
#pragma unroll
        for (int kb = 0; kb < 8; ++kb) {
            U16F a;
            const int off = (am * 512 + kb * 64 + kq * 16) ^ ((am & 7) << 4);
            a.u = *(const u32x4*)((const char*)xlds + off);
            acc = __builtin_amdgcn_mfma_f32_16x16x32_bf16(a.b, bfr[kb].b, acc, 0, 0, 0);
        }

        // ---- wait for h_{t-1} flags from all 32 peers of this group ----
        {
            int* fp = flags + g * CWG + (l & 31);
            int v = __hip_atomic_load(fp, __ATOMIC_RELAXED, __HIP_MEMORY_SCOPE_AGENT);
            if (!__all(v >= t)) {
                int guard = 0;
                do {
                    __builtin_amdgcn_s_sleep(1);
                    v = __hip_atomic_load(fp, __ATOMIC_RELAXED, __HIP_MEMORY_SCOPE_AGENT);
                    if (++guard > 4000000) { abortf = 1; break; }
                } while (!__all(v >= t));
            }
        }
        // No acquire fence needed: h loads below read at the coherence point
        // (sc0 sc1 bypass L1/L2), and writer ordered h-ACK before flag store.

        // ---- stage h tile -> LDS: 4 batched coalesced 16B cache-bypass loads ----
        {
            const char* hb0 = (const char*)ws + (size_t)rp * 131072;
            const unsigned long long a0 =
                (unsigned long long)(hb0 + ((size_t)(gb + w) << 10) + (c16 << 4));
            u32x4 h0, h1, h2, h3;
            asm volatile("global_load_dwordx4 %0, %1, off sc0 sc1" : "=v"(h0) : "v"(a0));
            asm volatile("global_load_dwordx4 %0, %1, off sc0 sc1" : "=v"(h1) : "v"(a0 + 4096));
            asm volatile("global_load_dwordx4 %0, %1, off sc0 sc1" : "=v"(h2) : "v"(a0 + 8192));
            asm volatile("global_load_dwordx4 %0, %1, off sc0 sc1" : "=v"(h3) : "v"(a0 + 12288));
            asm volatile("s_waitcnt vmcnt(0)" ::: "memory");
            __builtin_amdgcn_sched_barrier(0);
            const int m0 = w, m1 = w + 4, m2 = w + 8, m3 = w + 12;
            *(u32x4*)((char*)hlds + ((m0 * 1024 + c16 * 16) ^ ((m0 & 7) << 4))) = h0;
            *(u32x4*)((char*)hlds + ((m1 * 1024 + c16 * 16) ^ ((m1 & 7) << 4))) = h1;
            *(u32x4*)((char*)hlds + ((m2 * 1024 + c16 * 16) ^ ((m2 & 7) << 4))) = h2;
            *(u32x4*)((char*)hlds + ((m3 * 1024 + c16 * 16) ^ ((m3 & 7) << 4))) = h3;
        }
        __syncthreads();   // bar B
        if (abortf) break;

        // ---- h-part MFMA ----
#pragma unroll
        for (int kb = 0; kb < 16; ++kb) {
            U16F a;
            const int off = (am * 1024 + kb * 64 + kq * 16) ^ ((am & 7) << 4);
            a.u = *(const u32x4*)((const char*)hlds + off);
            acc = __builtin_amdgcn_mfma_f32_16x16x32_bf16(a.b, bfr[8 + kb].b, acc, 0, 0, 0);
        }
#pragma unroll
        for (int r = 0; r < 4; ++r) zbuf[w][kq * 4 + r][ncol] = acc[r];
        __syncthreads();   // bar C

        // ---- gates + cell update (two adjacent cells per thread, tid<128) ----
        if (tid < 128) {
            const float zi0 = zbuf[0][gm][jp * 2];
            const float zi1 = zbuf[0][gm][jp * 2 + 1];
            const float zf0 = zbuf[1][gm][jp * 2];
            const float zf1 = zbuf[1][gm][jp * 2 + 1];
            const float zg0 = zbuf[2][gm][jp * 2];
            const float zg1 = zbuf[2][gm][jp * 2 + 1];
            const float zo0 = zbuf[3][gm][jp * 2];
            const float zo1 = zbuf[3][gm][jp * 2 + 1];
            c0 = fsig(zf0) * c0 + fsig(zi0) * ftanh(zg0);
            c1 = fsig(zf1) * c1 + fsig(zi1) * ftanh(zg1);
            ph0 = fsig(zo0) * ftanh(c0);
            ph1 = fsig(zo1) * ftanh(c1);

            // h_t -> global: one sc1 32-bit store (2 bf16)
            const unsigned word = (unsigned)f2bf(ph0) | ((unsigned)f2bf(ph1) << 16);
            __hip_atomic_store(
                (unsigned*)(hbuf + (size_t)wp * (BB * UU) + (size_t)(gb + gm) * UU + unit0),
                word, __ATOMIC_RELAXED, __HIP_MEMORY_SCOPE_AGENT);
        }
        __syncthreads();   // bar D: drains h sc1 stores (out-store NOT pending here)
        if (tid == 0)
            __hip_atomic_store(flags + g * CWG + cw, t + 1,
                               __ATOMIC_RELAXED, __HIP_MEMORY_SCOPE_AGENT);
    }

    // final deferred out-store (t = TT-1)
    if (tid < 128) {
        f32x2 hv; hv[0] = ph0; hv[1] = ph1;
        __builtin_nontemporal_store(
            hv, (f32x2*)(out + ((size_t)(gb + gm) * TT + (TT - 1)) * UU + unit0));
    }
}

// proj_w [256][512] f32 -> pwT [512][256] bf16
__global__ void prep_kernel(const float* __restrict__ pw, unsigned short* __restrict__ pwT) {
    const int e = blockIdx.x * 256 + threadIdx.x;
    const int n = e >> 8, k = e & 255;
    pwT[e] = f2bf(pw[(size_t)k * UU + n]);
}

// residual GEMM + add h + layernorm, in-place on d_out. 16 rows / block.
__global__ void __launch_bounds__(256) ln_kernel(
    const float* __restrict__ x, const unsigned short* __restrict__ pwT,
    const float* __restrict__ pb, const float* __restrict__ gamma,
    const float* __restrict__ beta, float* __restrict__ out)
{
    const int tid = threadIdx.x;
    const int l = tid & 63;
    const int w = tid >> 6;
    const int r0 = blockIdx.x * 16;
    __shared__ __align__(16) float ybuf[16 * 516];

    // phase 0: coalesced float4 load of the out (lstm h) tile -> ybuf
#pragma unroll
    for (int i = 0; i < 8; ++i) {
        const int idx = tid + 256 * i;       // 0..2047 float4 chunks
        const int m = idx >> 7, c = idx & 127;
        const float4 v = *(const float4*)(out + (size_t)(r0 + m) * UU + c * 4);
        *(float4*)&ybuf[m * 516 + c * 4] = v;
    }

    const int ncol = l & 15, kq = l >> 4;
    U16F af[8];
    const int arow = r0 + ncol;
#pragma unroll
    for (int kb = 0; kb < 8; ++kb) {
        const float* src = x + (size_t)arow * FF + kb * 32 + kq * 8;
        const float4 v0 = *(const float4*)(src);
        const float4 v1 = *(const float4*)(src + 4);
        af[kb].u.x = f2bf(v0.x) | ((unsigned)f2bf(v0.y) << 16);
        af[kb].u.y = f2bf(v0.z) | ((unsigned)f2bf(v0.w) << 16);
        af[kb].u.z = f2bf(v1.x) | ((unsigned)f2bf(v1.y) << 16);
        af[kb].u.w = f2bf(v1.z) | ((unsigned)f2bf(v1.w) << 16);
    }
    __syncthreads();   // ybuf tile resident

#pragma unroll
    for (int nt = 0; nt < 8; ++nt) {
        const int colb = w * 128 + nt * 16;
        f32x4 acc = {0.f, 0.f, 0.f, 0.f};
#pragma unroll
        for (int kb = 0; kb < 8; ++kb) {
            U16F bf;
            bf.u = *(const u32x4*)(pwT + (size_t)(colb + ncol) * FF + kb * 32 + kq * 8);
            acc = __builtin_amdgcn_mfma_f32_16x16x32_bf16(af[kb].b, bf.b, acc, 0, 0, 0);
        }
        const int col = colb + ncol;
        const float pbv = pb[col];
#pragma unroll
        for (int r = 0; r < 4; ++r) {
            const int row = kq * 4 + r;
            ybuf[row * 516 + col] += acc[r] + pbv;   // unique (row,col) per thread
        }
    }
    __syncthreads();

    const int m = tid >> 4, j = tid & 15;
    float s = 0.f, s2 = 0.f;
#pragma unroll
    for (int i = 0; i < 32; ++i) {
        const float v = ybuf[m * 516 + j + 16 * i];
        s += v; s2 += v * v;
    }
#pragma unroll
    for (int mask = 1; mask < 16; mask <<= 1) {
        s += __shfl_xor(s, mask);
        s2 += __shfl_xor(s2, mask);
    }
    const float mean = s * (1.0f / 512.0f);
    const float var = s2 * (1.0f / 512.0f) - mean * mean;
    const float rs = rsqrtf(var + 1e-6f);

    // coalesced float4 normalize + write
#pragma unroll
    for (int i = 0; i < 8; ++i) {
        const int c4 = j + 16 * i;           // float4 group 0..127
        float4 v = *(const float4*)&ybuf[m * 516 + c4 * 4];
        const float4 g4 = *(const float4*)&gamma[c4 * 4];
        const float4 b4 = *(const float4*)&beta[c4 * 4];
        v.x = g4.x * ((v.x - mean) * rs) + b4.x;
        v.y = g4.y * ((v.y - mean) * rs) + b4.y;
        v.z = g4.z * ((v.z - mean) * rs) + b4.z;
        v.w = g4.w * ((v.w - mean) * rs) + b4.w;
        *(float4*)(out + (size_t)(r0 + m) * UU + c4 * 4) = v;
    }
}

extern "C" void kernel_launch(void* const* d_in, const int* in_sizes, int n_in,
                              void* d_out, int out_size, void* d_ws, size_t ws_size,
                              hipStream_t stream) {
    const float* x     = (const float*)d_in[0];
    const float* wk    = (const float*)d_in[1];
    const float* wr    = (const float*)d_in[2];
    const float* bias  = (const float*)d_in[3];
    const float* pw    = (const float*)d_in[4];
    const float* pb    = (const float*)d_in[5];
    const float* gamma = (const float*)d_in[6];
    const float* beta  = (const float*)d_in[7];
    float* out = (float*)d_out;

    if (ws_size < 528384) return;  // need ~516KB scratch

    unsigned short* pwT = (unsigned short*)((char*)d_ws + 266240);

    // zero h double-buffer + flags
    hipMemsetAsync(d_ws, 0, 263168, stream);
    hipLaunchKernelGGL(prep_kernel, dim3(512), dim3(256), 0, stream, pw, pwT);

    // cooperative launch: guarantees all 256 WGs co-resident (spin barriers)
    const float* a0 = x; const float* a1 = wk; const float* a2 = wr;
    const float* a3 = bias; float* a4 = out; void* a5 = d_ws;
    void* args[6] = {(void*)&a0, (void*)&a1, (void*)&a2, (void*)&a3, (void*)&a4, (void*)&a5};
    hipError_t ce = hipLaunchCooperativeKernel((const void*)lstm_kernel, dim3(256), dim3(256),
                                               args, 0, stream);
    if (ce != hipSuccess) {
        hipLaunchKernelGGL(lstm_kernel, dim3(256), dim3(256), 0, stream,
                           x, wk, wr, bias, out, d_ws);
    }

    hipLaunchKernelGGL(ln_kernel, dim3(BB * TT / 16), dim3(256), 0, stream,
                       x, pwT, pb, gamma, beta, out);
}